// Round 1
// baseline (244.529 us; speedup 1.0000x reference)
//
#include <hip/hip_runtime.h>
#include <math.h>

typedef __attribute__((ext_vector_type(8))) short bf16x8;
typedef __attribute__((ext_vector_type(4))) float f32x4;

__device__ __forceinline__ float wave_reduce(float v) {
#pragma unroll
    for (int off = 32; off > 0; off >>= 1) v += __shfl_down(v, off, 64);
    return v;
}

__device__ __forceinline__ unsigned short f2bf(float x) {
    unsigned u = __float_as_uint(x);
    u += 0x7FFFu + ((u >> 16) & 1u);   // round-to-nearest-even
    return (unsigned short)(u >> 16);
}

// Kernel 1: fp32 centers -> bf16 (zero-padded to Cpad rows) + dist2[r] = ||centers[r]||^2
__global__ __launch_bounds__(128) void prep_kernel(const float4* __restrict__ cent4,
                                                   ushort4* __restrict__ xb,
                                                   float* __restrict__ dist2,
                                                   int C, int d4) {
    const int r = blockIdx.x;
    const int t = threadIdx.x;
    __shared__ float sm[2];
    float s = 0.f;
    for (int c = t; c < d4; c += blockDim.x) {
        float4 f = make_float4(0.f, 0.f, 0.f, 0.f);
        if (r < C) f = cent4[(size_t)r * d4 + c];
        s += f.x * f.x + f.y * f.y + f.z * f.z + f.w * f.w;
        ushort4 h;
        h.x = f2bf(f.x); h.y = f2bf(f.y); h.z = f2bf(f.z); h.w = f2bf(f.w);
        xb[(size_t)r * d4 + c] = h;
    }
    s = wave_reduce(s);
    const int lane = t & 63, w = t >> 6;
    if (lane == 0) sm[w] = s;
    __syncthreads();
    if (t == 0) {
        float tot = sm[0];
        if (blockDim.x > 64) tot += sm[1];
        dist2[r] = (r < C) ? tot : 1.0f;   // pad rows get dummy norm (masked later)
    }
}

// Kernel 2: center loss. Grid-stride over float4 elements of feat.
__global__ __launch_bounds__(256) void center_kernel(const int* __restrict__ y,
                                                     const float4* __restrict__ feat4,
                                                     const float4* __restrict__ cent4,
                                                     float* __restrict__ out,
                                                     int n4, int d4, float scale) {
    __shared__ float sm[4];
    const int stride = gridDim.x * 256;
    float s = 0.f;
    int i = blockIdx.x * 256 + threadIdx.x;
    if ((stride % d4) == 0) {
        // fast path: column index invariant across the grid-stride loop
        if (i < n4) {
            int row = i / d4;
            const int col = i - row * d4;
            const int rstep = stride / d4;
            for (; i < n4; i += stride, row += rstep) {
                const int cls = y[row];
                float4 f = feat4[i];
                float4 c = cent4[(size_t)cls * d4 + col];
                float dx = f.x - c.x, dy = f.y - c.y, dz = f.z - c.z, dw = f.w - c.w;
                s += dx * dx + dy * dy + dz * dz + dw * dw;
            }
        }
    } else {
        for (; i < n4; i += stride) {
            int row = i / d4;
            int col = i - row * d4;
            const int cls = y[row];
            float4 f = feat4[i];
            float4 c = cent4[(size_t)cls * d4 + col];
            float dx = f.x - c.x, dy = f.y - c.y, dz = f.z - c.z, dw = f.w - c.w;
            s += dx * dx + dy * dy + dz * dz + dw * dw;
        }
    }
    s = wave_reduce(s);
    const int lane = threadIdx.x & 63, w = threadIdx.x >> 6;
    if (lane == 0) sm[w] = s;
    __syncthreads();
    if (threadIdx.x == 0) {
        float tot = sm[0] + sm[1] + sm[2] + sm[3];
        atomicAdd(out, tot * scale);
    }
}

// Kernel 3: angular loss via bf16 MFMA gram tiles. One 16x16 output tile per wave.
// A-frag: A[m=lane&15][k=quad*8+j]; B-frag: B[n=lane&15][k=quad*8+j] (B = A^T row-load);
// C/D: col=lane&15, row=quad*4+reg.
__global__ __launch_bounds__(256) void ang_kernel(const unsigned short* __restrict__ xb,
                                                  const float* __restrict__ dist2,
                                                  float* __restrict__ out,
                                                  int C, int D, int ntile,
                                                  float ct, float scale) {
    __shared__ float sm[4];
    const int wid = threadIdx.x >> 6;
    const int w = blockIdx.x * 4 + wid;
    float local = 0.f;
    if (w < ntile * ntile) {
        const int ti = w / ntile;
        const int tj = w - ti * ntile;
        const int lane = threadIdx.x & 63;
        const int n = lane & 15;
        const int quad = lane >> 4;
        const int dv = D >> 3;   // bf16x8 units per row
        const bf16x8* ap = (const bf16x8*)xb + (size_t)(ti * 16 + n) * dv + quad;
        const bf16x8* bp = (const bf16x8*)xb + (size_t)(tj * 16 + n) * dv + quad;
        f32x4 acc = {0.f, 0.f, 0.f, 0.f};
        const int steps = D >> 5;   // K-chunks of 32
#pragma unroll 8
        for (int st = 0; st < steps; ++st) {
            bf16x8 a = ap[st * 4];
            bf16x8 b = bp[st * 4];
            acc = __builtin_amdgcn_mfma_f32_16x16x32_bf16(a, b, acc, 0, 0, 0);
        }
        const int gj = tj * 16 + n;
        const float dj = dist2[gj];
#pragma unroll
        for (int rr = 0; rr < 4; ++rr) {
            const int gi = ti * 16 + quad * 4 + rr;
            if (gi < C && gj < C && gi != gj) {
                float sim = acc[rr] * rsqrtf(dist2[gi] * dj);
                float dlt = sim - ct;
                local += dlt * dlt;
            }
        }
    }
    local = wave_reduce(local);
    if ((threadIdx.x & 63) == 0) sm[wid] = local;
    __syncthreads();
    if (threadIdx.x == 0) {
        float tot = sm[0] + sm[1] + sm[2] + sm[3];
        atomicAdd(out, tot * scale);
    }
}

extern "C" void kernel_launch(void* const* d_in, const int* in_sizes, int n_in,
                              void* d_out, int out_size, void* d_ws, size_t ws_size,
                              hipStream_t stream) {
    const int* y = (const int*)d_in[0];
    const float* feat = (const float*)d_in[1];
    const float* centers = (const float*)d_in[2];

    const int B = in_sizes[0];
    const int D = in_sizes[1] / B;
    const int C = in_sizes[2] / D;
    const int d4 = D / 4;
    const int ntile = (C + 15) / 16;
    const int Cpad = ntile * 16;

    // ct = costheta(C): static recurrence in double, matches Python reference.
    const int nd = C - 1;
    double r = 0.0;
    if (nd >= 2) {
        r = 0.5;
        for (int i = 3; i <= nd; ++i) r = 0.5 / sqrt(1.0 - r * r);
    }
    const float ct = (float)(2.0 * r * r - 1.0);

    float* outp = (float*)d_out;
    char* ws = (char*)d_ws;
    unsigned short* xb = (unsigned short*)ws;               // Cpad x D bf16
    size_t xb_bytes = (size_t)Cpad * D * sizeof(unsigned short);
    float* dist2 = (float*)(ws + ((xb_bytes + 255) & ~(size_t)255));

    hipMemsetAsync(d_out, 0, sizeof(float), stream);

    prep_kernel<<<Cpad, 128, 0, stream>>>((const float4*)centers, (ushort4*)xb, dist2, C, d4);

    const int n4 = B * d4;
    const float cen_scale = (float)(0.5 / (double)B);
    center_kernel<<<2048, 256, 0, stream>>>(y, (const float4*)feat, (const float4*)centers,
                                            outp, n4, d4, cen_scale);

    const int ntile2 = ntile * ntile;
    const int ang_blocks = (ntile2 + 3) / 4;
    const float ang_scale = (float)(1.0 / (0.5 * (double)C * (double)(C - 1)));
    ang_kernel<<<ang_blocks, 256, 0, stream>>>(xb, dist2, outp, C, D, ntile, ct, ang_scale);
}

// Round 3
// 224.490 us; speedup vs baseline: 1.0893x; 1.0893x over previous
//
#include <hip/hip_runtime.h>
#include <math.h>

typedef __attribute__((ext_vector_type(8))) short bf16x8;
typedef __attribute__((ext_vector_type(4))) float f32x4;
typedef __attribute__((ext_vector_type(4))) float vf4;   // native vec for nontemporal builtins

__device__ __forceinline__ float wave_reduce(float v) {
#pragma unroll
    for (int off = 32; off > 0; off >>= 1) v += __shfl_down(v, off, 64);
    return v;
}

__device__ __forceinline__ unsigned short f2bf(float x) {
    unsigned u = __float_as_uint(x);
    u += 0x7FFFu + ((u >> 16) & 1u);   // round-to-nearest-even
    return (unsigned short)(u >> 16);
}

// Kernel 1: fp32 centers -> bf16 (zero-padded to Cpad rows) + dist2[r] = ||centers[r]||^2.
// Block 0 also zero-inits out[0] (runs before any atomic user via stream order).
__global__ __launch_bounds__(128) void prep_kernel(const float4* __restrict__ cent4,
                                                   ushort4* __restrict__ xb,
                                                   float* __restrict__ dist2,
                                                   float* __restrict__ out,
                                                   int C, int d4) {
    const int r = blockIdx.x;
    const int t = threadIdx.x;
    if (r == 0 && t == 0) out[0] = 0.f;
    __shared__ float sm[2];
    float s = 0.f;
    for (int c = t; c < d4; c += blockDim.x) {
        float4 f = make_float4(0.f, 0.f, 0.f, 0.f);
        if (r < C) f = cent4[(size_t)r * d4 + c];
        s += f.x * f.x + f.y * f.y + f.z * f.z + f.w * f.w;
        ushort4 h;
        h.x = f2bf(f.x); h.y = f2bf(f.y); h.z = f2bf(f.z); h.w = f2bf(f.w);
        xb[(size_t)r * d4 + c] = h;
    }
    s = wave_reduce(s);
    const int lane = t & 63, w = t >> 6;
    if (lane == 0) sm[w] = s;
    __syncthreads();
    if (t == 0) {
        float tot = sm[0];
        if (blockDim.x > 64) tot += sm[1];
        dist2[r] = (r < C) ? tot : 1.0f;   // pad rows get dummy norm (masked later)
    }
}

// Kernel 2 (fused): blocks [0, ang_blocks) do the angular MFMA tiles (L2/MFMA-bound);
// blocks [ang_blocks, ang_blocks+center_blocks) do the center loss (HBM-bound).
// The two phases use disjoint resources and overlap on the device.
__global__ __launch_bounds__(256) void fused_kernel(const int* __restrict__ y,
                                                    const vf4* __restrict__ feat4,
                                                    const float4* __restrict__ cent4,
                                                    const unsigned short* __restrict__ xb,
                                                    const float* __restrict__ dist2,
                                                    float* __restrict__ out,
                                                    int n4, int d4, float cen_scale,
                                                    int C, int D, int ntile,
                                                    float ct, float ang_scale,
                                                    int ang_blocks, int center_blocks) {
    __shared__ float sm[4];
    const int lane = threadIdx.x & 63;
    const int wid = threadIdx.x >> 6;

    if ((int)blockIdx.x < ang_blocks) {
        // ---------------- angular path: one 16x16 gram tile per wave ----------------
        const int w = blockIdx.x * 4 + wid;
        float local = 0.f;
        if (w < ntile * ntile) {
            const int ti = w / ntile;
            const int tj = w - ti * ntile;
            const int n = lane & 15;
            const int quad = lane >> 4;
            const int dv = D >> 3;   // bf16x8 units per row
            const bf16x8* ap = (const bf16x8*)xb + (size_t)(ti * 16 + n) * dv + quad;
            const bf16x8* bp = (const bf16x8*)xb + (size_t)(tj * 16 + n) * dv + quad;
            f32x4 acc = {0.f, 0.f, 0.f, 0.f};
            const int steps = D >> 5;   // K-chunks of 32
#pragma unroll 8
            for (int st = 0; st < steps; ++st) {
                bf16x8 a = ap[st * 4];
                bf16x8 b = bp[st * 4];
                acc = __builtin_amdgcn_mfma_f32_16x16x32_bf16(a, b, acc, 0, 0, 0);
            }
            const int gj = tj * 16 + n;
            const float dj = dist2[gj];
#pragma unroll
            for (int rr = 0; rr < 4; ++rr) {
                const int gi = ti * 16 + quad * 4 + rr;
                if (gi < C && gj < C && gi != gj) {
                    float sim = acc[rr] * rsqrtf(dist2[gi] * dj);
                    float dlt = sim - ct;
                    local += dlt * dlt;
                }
            }
        }
        local = wave_reduce(local);
        if (lane == 0) sm[wid] = local;
        __syncthreads();
        if (threadIdx.x == 0) {
            float tot = sm[0] + sm[1] + sm[2] + sm[3];
            atomicAdd(out, tot * ang_scale);
        }
    } else {
        // ---------------- center path: grid-stride over float4 elements of feat ----
        const int cb = blockIdx.x - ang_blocks;
        const int stride = center_blocks * 256;
        float s = 0.f;
        int i = cb * 256 + threadIdx.x;
        if ((stride % d4) == 0) {
            // fast path: column index invariant across the grid-stride loop
            if (i < n4) {
                int row = i / d4;
                const int col = i - row * d4;
                const int rstep = stride / d4;
                for (; i < n4; i += stride, row += rstep) {
                    const int cls = y[row];
                    vf4 f = __builtin_nontemporal_load(feat4 + i);
                    float4 c = cent4[(size_t)cls * d4 + col];
                    float dx = f.x - c.x, dy = f.y - c.y, dz = f.z - c.z, dw = f.w - c.w;
                    s += dx * dx + dy * dy + dz * dz + dw * dw;
                }
            }
        } else {
            for (; i < n4; i += stride) {
                int row = i / d4;
                int col = i - row * d4;
                const int cls = y[row];
                vf4 f = __builtin_nontemporal_load(feat4 + i);
                float4 c = cent4[(size_t)cls * d4 + col];
                float dx = f.x - c.x, dy = f.y - c.y, dz = f.z - c.z, dw = f.w - c.w;
                s += dx * dx + dy * dy + dz * dz + dw * dw;
            }
        }
        s = wave_reduce(s);
        if (lane == 0) sm[wid] = s;
        __syncthreads();
        if (threadIdx.x == 0) {
            float tot = sm[0] + sm[1] + sm[2] + sm[3];
            atomicAdd(out, tot * cen_scale);
        }
    }
}

extern "C" void kernel_launch(void* const* d_in, const int* in_sizes, int n_in,
                              void* d_out, int out_size, void* d_ws, size_t ws_size,
                              hipStream_t stream) {
    const int* y = (const int*)d_in[0];
    const float* feat = (const float*)d_in[1];
    const float* centers = (const float*)d_in[2];

    const int B = in_sizes[0];
    const int D = in_sizes[1] / B;
    const int C = in_sizes[2] / D;
    const int d4 = D / 4;
    const int ntile = (C + 15) / 16;
    const int Cpad = ntile * 16;

    // ct = costheta(C): static recurrence in double, matches Python reference.
    const int nd = C - 1;
    double r = 0.0;
    if (nd >= 2) {
        r = 0.5;
        for (int i = 3; i <= nd; ++i) r = 0.5 / sqrt(1.0 - r * r);
    }
    const float ct = (float)(2.0 * r * r - 1.0);

    float* outp = (float*)d_out;
    char* ws = (char*)d_ws;
    unsigned short* xb = (unsigned short*)ws;               // Cpad x D bf16
    size_t xb_bytes = (size_t)Cpad * D * sizeof(unsigned short);
    float* dist2 = (float*)(ws + ((xb_bytes + 255) & ~(size_t)255));

    prep_kernel<<<Cpad, 128, 0, stream>>>((const float4*)centers, (ushort4*)xb, dist2,
                                          outp, C, d4);

    const int n4 = B * d4;
    const float cen_scale = (float)(0.5 / (double)B);
    const float ang_scale = (float)(1.0 / (0.5 * (double)C * (double)(C - 1)));
    const int ntile2 = ntile * ntile;
    const int ang_blocks = (ntile2 + 3) / 4;
    const int center_blocks = 2048;

    fused_kernel<<<ang_blocks + center_blocks, 256, 0, stream>>>(
        y, (const vf4*)feat, (const float4*)centers, xb, dist2, outp,
        n4, d4, cen_scale, C, D, ntile, ct, ang_scale, ang_blocks, center_blocks);
}